// Round 1
// baseline (105.544 us; speedup 1.0000x reference)
//
#include <hip/hip_runtime.h>
#include <hip/hip_bf16.h>
#include <math.h>

#define N_NODES 2048
#define L_DIM   16
#define HEADS   4
#define DDIM    64
#define TJ      128

// ws layout (float offsets). Bmax occupies the first 4 uints.
#define OFF_G     256
#define OFF_B     (OFF_G + N_NODES*DDIM)            // 131328
#define OFF_PAGG  (OFF_B + N_NODES*HEADS)           // 139520
#define OFF_PCNT  (OFF_PAGG + 32*L_DIM*DDIM)        // 172288
#define OFF_CENT  (OFF_PCNT + 32*L_DIM)             // 172800

__device__ __forceinline__ float leaky02(float v) {
    // slope 0.2 < 1  =>  leaky(x) = max(x, 0.2x)
    return fmaxf(v, 0.2f * v);
}

// ---------------------------------------------------------------------------
// Kernel A: ohm fill + g = pin @ W_l^T  + softmax bound b[i,h] + per-head Bmax
// grid 512 x 256 : block = 4 rows, thread (row, out-col o)
// ---------------------------------------------------------------------------
__global__ __launch_bounds__(256) void k_proj(
    const float* __restrict__ x, const float* __restrict__ ohm_labels,
    const float* __restrict__ Wl, const float* __restrict__ Wattn,
    float* __restrict__ g, float* __restrict__ b, unsigned* __restrict__ Bmax)
{
    int t = threadIdx.x;
    int i = blockIdx.x * 4 + (t >> 6);
    int o = t & 63;

    float oh[16];
    float rs = 0.f;
    #pragma unroll
    for (int k = 0; k < 16; ++k) { float v = ohm_labels[i*16 + k]; oh[k] = v; rs += v; }
    if (rs == 0.f) {
        #pragma unroll
        for (int k = 0; k < 16; ++k) oh[k] = 1.0f / 16.0f;
    }

    float acc = 0.f;
    #pragma unroll 8
    for (int k = 0; k < 64; ++k) acc = fmaf(x[i*64 + k], Wl[o*80 + k], acc);
    #pragma unroll
    for (int k = 0; k < 16; ++k) acc = fmaf(oh[k], Wl[o*80 + 64 + k], acc);

    g[i*64 + o] = acc;

    // bound contribution |w_f| * |g|
    float part = fabsf(Wattn[o & 15]) * fabsf(acc);
    #pragma unroll
    for (int d = 1; d < 16; d <<= 1) part += __shfl_xor(part, d, 16);
    if ((o & 15) == 0) {
        b[i*4 + (o >> 4)] = part;
        atomicMax(&Bmax[o >> 4], __float_as_uint(part));  // part >= 0: bit order == float order
    }
}

// ---------------------------------------------------------------------------
// Kernel B: flash-style attention. grid 512 x 256.
// block = 4 i-rows; pair = (slot 0..1, head 0..3) x 32 subs; thread owns 2 i's.
// fixed per-(i,h) shift m = b_i + Bmax_h  => no online max, no rescale.
// ---------------------------------------------------------------------------
__global__ __launch_bounds__(256) void k_attn(
    const float* __restrict__ g, const float* __restrict__ b,
    const unsigned* __restrict__ Bmax, const float* __restrict__ Wattn,
    float* __restrict__ hout)
{
    __shared__ float lds[TJ * 68];
    int t = threadIdx.x;
    int pair = t >> 5, sub = t & 31;
    int slot = pair >> 2, h = pair & 3;
    int ia = blockIdx.x * 4 + slot * 2;
    int ic = ia + 1;

    float w[16], gA[16], gB[16];
    #pragma unroll
    for (int f = 0; f < 16; ++f) {
        w[f]  = Wattn[f];
        gA[f] = g[ia*64 + h*16 + f];
        gB[f] = g[ic*64 + h*16 + f];
    }
    float Bh = __uint_as_float(Bmax[h]);
    float mA = b[ia*4 + h] + Bh;
    float mB = b[ic*4 + h] + Bh;

    float lA = 0.f, lB = 0.f;
    float accA[16], accB[16];
    #pragma unroll
    for (int f = 0; f < 16; ++f) { accA[f] = 0.f; accB[f] = 0.f; }

    for (int tile = 0; tile < N_NODES / TJ; ++tile) {
        __syncthreads();
        const float4* src = (const float4*)(g + tile * TJ * 64);
        #pragma unroll
        for (int q = 0; q < 8; ++q) {
            int v = t + q * 256;
            float4 dv = src[v];
            *(float4*)&lds[(v >> 4) * 68 + (v & 15) * 4] = dv;
        }
        __syncthreads();

        #pragma unroll
        for (int k = 0; k < TJ / 32; ++k) {
            const float* gj = &lds[(k * 32 + sub) * 68 + h * 16];
            float4 v0 = *(const float4*)&gj[0];
            float4 v1 = *(const float4*)&gj[4];
            float4 v2 = *(const float4*)&gj[8];
            float4 v3 = *(const float4*)&gj[12];
            float gv[16] = { v0.x, v0.y, v0.z, v0.w,
                             v1.x, v1.y, v1.z, v1.w,
                             v2.x, v2.y, v2.z, v2.w,
                             v3.x, v3.y, v3.z, v3.w };
            float eA = 0.f, eB = 0.f;
            #pragma unroll
            for (int f = 0; f < 16; ++f) {
                float sA = gA[f] + gv[f]; sA = fmaxf(sA, 0.2f * sA);
                float sB = gB[f] + gv[f]; sB = fmaxf(sB, 0.2f * sB);
                eA = fmaf(w[f], sA, eA);
                eB = fmaf(w[f], sB, eB);
            }
            float pA = __expf(eA - mA);
            float pB = __expf(eB - mB);
            lA += pA; lB += pB;
            #pragma unroll
            for (int f = 0; f < 16; ++f) {
                accA[f] = fmaf(pA, gv[f], accA[f]);
                accB[f] = fmaf(pB, gv[f], accB[f]);
            }
        }
    }

    // butterfly sum over the 32 subs (within one half-wave; no max-merge needed)
    #pragma unroll
    for (int d2 = 1; d2 < 32; d2 <<= 1) {
        lA += __shfl_xor(lA, d2);
        lB += __shfl_xor(lB, d2);
        #pragma unroll
        for (int f = 0; f < 16; ++f) {
            accA[f] += __shfl_xor(accA[f], d2);
            accB[f] += __shfl_xor(accB[f], d2);
        }
    }

    if (sub == 0) {
        float rA = 1.0f / fmaxf(lA, 1e-35f);
        float rB = 1.0f / fmaxf(lB, 1e-35f);
        #pragma unroll
        for (int f = 0; f < 16; ++f) {
            hout[ia*64 + h*16 + f] = leaky02(accA[f] * rA);
            hout[ic*64 + h*16 + f] = leaky02(accB[f] * rB);
        }
    }
}

// ---------------------------------------------------------------------------
// Kernel C1: partial centroid aggregation. grid 32 x 256, block = 64 i-rows.
// ---------------------------------------------------------------------------
__global__ __launch_bounds__(256) void k_cpart(
    const float* __restrict__ ohm_labels, const float* __restrict__ hout,
    float* __restrict__ pagg, float* __restrict__ pcnt)
{
    __shared__ float srs[64];
    int t = threadIdx.x, bb = blockIdx.x;
    int d = t & 63, lg = t >> 6;   // this thread covers l = lg + 4q

    if (t < 64) {
        float rs = 0.f;
        #pragma unroll
        for (int k = 0; k < 16; ++k) rs += ohm_labels[(bb*64 + t)*16 + k];
        srs[t] = rs;
    }
    __syncthreads();

    float agg[4] = {0.f, 0.f, 0.f, 0.f};
    float cnt[4] = {0.f, 0.f, 0.f, 0.f};
    for (int ii = 0; ii < 64; ++ii) {
        int i = bb*64 + ii;
        bool unl = (srs[ii] == 0.f);
        float hv = hout[i*64 + d];
        #pragma unroll
        for (int q = 0; q < 4; ++q) {
            int l = lg + 4*q;
            float ov = unl ? (1.0f/16.0f) : ohm_labels[i*16 + l];
            agg[q] = fmaf(ov, hv, agg[q]);
            if (d == 0) cnt[q] += ov;
        }
    }
    #pragma unroll
    for (int q = 0; q < 4; ++q) {
        pagg[bb*1024 + (lg + 4*q)*64 + d] = agg[q];
        if (d == 0) pcnt[bb*16 + lg + 4*q] = cnt[q];
    }
}

// ---------------------------------------------------------------------------
// Kernel C2: final centroid reduce (1 block, deterministic order)
// ---------------------------------------------------------------------------
__global__ __launch_bounds__(256) void k_cfinal(
    const float* __restrict__ pagg, const float* __restrict__ pcnt,
    float* __restrict__ cent, float* __restrict__ missing_out)
{
    __shared__ float scnt[16];
    int t = threadIdx.x;
    if (t < 16) {
        float c = 0.f;
        for (int bb = 0; bb < 32; ++bb) c += pcnt[bb*16 + t];
        scnt[t] = c;
        missing_out[t] = (c == 0.f) ? 1.0f : 0.0f;
    }
    __syncthreads();
    #pragma unroll
    for (int q = 0; q < 4; ++q) {
        int o = q*256 + t;
        float a = 0.f;
        for (int bb = 0; bb < 32; ++bb) a += pagg[bb*1024 + o];
        float c = scnt[o >> 6];
        cent[o] = (c == 0.f) ? 0.f : a / c;
    }
}

// ---------------------------------------------------------------------------
// Kernel C3: scores[i,l] = -||h_i - cent_l||_2 . grid 128 x 256.
// ---------------------------------------------------------------------------
__global__ __launch_bounds__(256) void k_scores(
    const float* __restrict__ hout, const float* __restrict__ cent,
    float* __restrict__ scores)
{
    __shared__ float sc[1024];
    int t = threadIdx.x;
    #pragma unroll
    for (int q = 0; q < 4; ++q) sc[q*256 + t] = cent[q*256 + t];
    __syncthreads();

    int i = blockIdx.x * 16 + (t >> 4);
    int l = t & 15;
    float s = 0.f;
    #pragma unroll 16
    for (int d = 0; d < 64; ++d) {
        float diff = hout[i*64 + d] - sc[l*64 + d];
        s = fmaf(diff, diff, s);
    }
    scores[i*16 + l] = -sqrtf(s);
}

// ---------------------------------------------------------------------------
extern "C" void kernel_launch(void* const* d_in, const int* in_sizes, int n_in,
                              void* d_out, int out_size, void* d_ws, size_t ws_size,
                              hipStream_t stream)
{
    const float* x          = (const float*)d_in[0];
    const float* ohm_labels = (const float*)d_in[1];
    const float* Wl         = (const float*)d_in[2];
    const float* Wattn      = (const float*)d_in[3];

    float* W     = (float*)d_ws;
    float* g     = W + OFF_G;
    float* b     = W + OFF_B;
    float* pagg  = W + OFF_PAGG;
    float* pcnt  = W + OFF_PCNT;
    float* cent  = W + OFF_CENT;
    unsigned* Bmax = (unsigned*)d_ws;

    float* scores  = (float*)d_out;
    float* hout    = scores + N_NODES*L_DIM;
    float* missing = scores + N_NODES*L_DIM + N_NODES*DDIM;

    hipMemsetAsync(d_ws, 0, 16, stream);  // zero Bmax[4]
    k_proj  <<<512, 256, 0, stream>>>(x, ohm_labels, Wl, Wattn, g, b, Bmax);
    k_attn  <<<512, 256, 0, stream>>>(g, b, Bmax, Wattn, hout);
    k_cpart <<<32,  256, 0, stream>>>(ohm_labels, hout, pagg, pcnt);
    k_cfinal<<<1,   256, 0, stream>>>(pagg, pcnt, cent, missing);
    k_scores<<<128, 256, 0, stream>>>(hout, cent, scores);
}

// Round 3
// 68.361 us; speedup vs baseline: 1.5439x; 1.5439x over previous
//
#include <hip/hip_runtime.h>
#include <hip/hip_bf16.h>
#include <math.h>

#define C1F  0.577078016f   // 0.4 * log2(e)
#define C2F  0.865617024f   // 0.6 * log2(e)
#define KL2E 1.44269504f

// ws byte offsets
#define WS_CNT 0                          // 16 x i64
#define WS_AGG 128                        // 1024 x i64  (ends 8320)
#define WS_G   8320                       // 2048*64 f32
#define WS_DCL (8320 + 524288)            // 2048*4 f32
#define WS_BSC (8320 + 524288 + 32768)    // 2048*4 f32  (ends 598144)

// ---------------------------------------------------------------------------
// k_proj: ohm fill + g = pin @ Wl^T + per-(i,h) log2-domain consts + cnt
// grid 512 x 256 : block = 4 rows, thread = (row, out-col o)
// ---------------------------------------------------------------------------
__global__ __launch_bounds__(256) void k_proj(
    const float* __restrict__ x, const float* __restrict__ ohm,
    const float* __restrict__ Wl, const float* __restrict__ Wattn,
    unsigned char* __restrict__ ws)
{
    float* g   = (float*)(ws + WS_G);
    float* dcl = (float*)(ws + WS_DCL);
    float* bsc = (float*)(ws + WS_BSC);
    unsigned long long* cnt = (unsigned long long*)(ws + WS_CNT);

    int t = threadIdx.x;
    int r = blockIdx.x * 4 + (t >> 6);
    int o = t & 63;

    float oh[16]; float rs = 0.f;
    #pragma unroll
    for (int k = 0; k < 16; ++k) { float v = ohm[r*16+k]; oh[k] = v; rs += v; }
    if (rs == 0.f) {
        #pragma unroll
        for (int k = 0; k < 16; ++k) oh[k] = 0.0625f;
    }

    float acc = 0.f;
    #pragma unroll 8
    for (int k = 0; k < 64; ++k) acc = fmaf(x[r*64+k], Wl[o*80+k], acc);
    #pragma unroll
    for (int k = 0; k < 16; ++k) acc = fmaf(oh[k], Wl[o*80+64+k], acc);
    g[r*64 + o] = acc;

    float wv  = Wattn[o & 15];
    float dot = wv * acc;                    // -> d_i,h
    float bnd = fabsf(wv) * fabsf(acc);      // -> b_i,h
    #pragma unroll
    for (int m2 = 1; m2 < 16; m2 <<= 1) {
        dot += __shfl_xor(dot, m2);
        bnd += __shfl_xor(bnd, m2);
    }
    if ((o & 15) == 0) {
        int h = o >> 4;
        dcl[r*4 + h] = C2F * dot;                  // log2-domain 0.6*d_j
        bsc[r*4 + h] = C2F * dot - KL2E * bnd;     // log2-domain (0.6*d_i - b_i)
    }
    if (t < 16) {  // exact label counts, fixed-point 2^20 (ohm in {0,1,1/16})
        float c = 0.f;
        for (int rr = 0; rr < 4; ++rr) {
            int r2 = blockIdx.x*4 + rr; float s = 0.f;
            #pragma unroll
            for (int k = 0; k < 16; ++k) s += ohm[r2*16+k];
            c += (s == 0.f) ? 0.0625f : ohm[r2*16+t];
        }
        atomicAdd(&cnt[t], (unsigned long long)__float2ll_rn(c * 1048576.0f));
    }
}

// ---------------------------------------------------------------------------
// k_attn: flash attention, fixed shift m_i = b_i (no online max, no rescale).
// grid 512 x 512. wave = (ipair, h); thread owns rows {iA,iB}, head h, j%64.
// Tail: per-block centroid partial agg -> int64 fixed-point atomics (determ.)
// ---------------------------------------------------------------------------
__global__ __launch_bounds__(512, 4) void k_attn(
    const float* __restrict__ ohm, const float* __restrict__ Wattn,
    unsigned char* __restrict__ ws, float* __restrict__ hout)
{
    float* g   = (float*)(ws + WS_G);
    float* dcl = (float*)(ws + WS_DCL);
    float* bsc = (float*)(ws + WS_BSC);
    unsigned long long* agg = (unsigned long long*)(ws + WS_AGG);

    __shared__ float glds[128*68];   // 34,816 B
    __shared__ float dlds[128*5];    //  2,560 B
    __shared__ float shh[256];
    __shared__ float ohmf[64];

    int t = threadIdx.x, bid = blockIdx.x;
    int ipair = t >> 8;          // 0..1
    int h     = (t >> 6) & 3;
    int sub   = t & 63;
    int iA = bid*4 + ipair*2;
    int iB = iA + 1;

    float w[16], gA[16], gB[16];
    #pragma unroll
    for (int f = 0; f < 16; ++f) {
        w[f]  = __uint_as_float(__builtin_amdgcn_readfirstlane(__float_as_uint(Wattn[f])));
        gA[f] = g[iA*64 + h*16 + f];
        gB[f] = g[iB*64 + h*16 + f];
    }
    float baseA = bsc[iA*4 + h];
    float baseB = bsc[iB*4 + h];

    float accA[16], accB[16];
    #pragma unroll
    for (int f = 0; f < 16; ++f) { accA[f] = 0.f; accB[f] = 0.f; }
    float lA = 0.f, lB = 0.f;

    for (int tile = 0; tile < 16; ++tile) {
        __syncthreads();
        const float4* srcg = (const float4*)(g + tile*8192);
        #pragma unroll
        for (int q = 0; q < 4; ++q) {
            int v = t + q*512;
            float4 d4 = srcg[v];
            *(float4*)&glds[(v>>4)*68 + (v&15)*4] = d4;
        }
        if (t < 128) {
            float4 dv = ((const float4*)(dcl + tile*512))[t];
            dlds[t*5+0] = dv.x; dlds[t*5+1] = dv.y;
            dlds[t*5+2] = dv.z; dlds[t*5+3] = dv.w;
        }
        __syncthreads();

        #pragma unroll
        for (int k = 0; k < 2; ++k) {
            int jl = k*64 + sub;
            float dj = dlds[jl*5 + h];
            const float* gj = &glds[jl*68 + h*16];
            float4 v0 = *(const float4*)&gj[0];
            float4 v1 = *(const float4*)&gj[4];
            float4 v2 = *(const float4*)&gj[8];
            float4 v3 = *(const float4*)&gj[12];
            float gv[16] = { v0.x,v0.y,v0.z,v0.w, v1.x,v1.y,v1.z,v1.w,
                             v2.x,v2.y,v2.z,v2.w, v3.x,v3.y,v3.z,v3.w };
            float sA = 0.f, sB = 0.f;
            #pragma unroll
            for (int f = 0; f < 16; ++f) {
                float ta = gA[f] + gv[f];
                float tb = gB[f] + gv[f];
                sA = fmaf(w[f], fabsf(ta), sA);   // |.| = free VOP3 modifier
                sB = fmaf(w[f], fabsf(tb), sB);
            }
            float pA = exp2f(fmaf(C1F, sA, baseA + dj));
            float pB = exp2f(fmaf(C1F, sB, baseB + dj));
            lA += pA; lB += pB;
            #pragma unroll
            for (int f = 0; f < 16; ++f) {
                accA[f] = fmaf(pA, gv[f], accA[f]);
                accB[f] = fmaf(pB, gv[f], accB[f]);
            }
        }
    }

    // full-wave butterfly (fixed shift => plain sums)
    #pragma unroll
    for (int m2 = 1; m2 < 64; m2 <<= 1) {
        lA += __shfl_xor(lA, m2);
        lB += __shfl_xor(lB, m2);
        #pragma unroll
        for (int f = 0; f < 16; ++f) {
            accA[f] += __shfl_xor(accA[f], m2);
            accB[f] += __shfl_xor(accB[f], m2);
        }
    }

    if (sub == 0) {
        float rA = 1.0f / lA, rB = 1.0f / lB;
        #pragma unroll
        for (int f = 0; f < 16; ++f) {
            float hA = accA[f]*rA; hA = fmaxf(hA, 0.2f*hA);
            float hB = accB[f]*rB; hB = fmaxf(hB, 0.2f*hB);
            hout[iA*64 + h*16 + f] = hA;
            hout[iB*64 + h*16 + f] = hB;
            shh[(ipair*2    )*64 + h*16 + f] = hA;
            shh[(ipair*2 + 1)*64 + h*16 + f] = hB;
        }
    }
    if (t < 64) {   // filled ohm for the block's 4 rows
        int rr = t >> 4, l = t & 15;
        float v = ohm[(bid*4 + rr)*16 + l];
        float s = v;
        #pragma unroll
        for (int m2 = 1; m2 < 16; m2 <<= 1) s += __shfl_xor(s, m2);
        ohmf[rr*16 + l] = (s == 0.f) ? 0.0625f : v;
    }
    __syncthreads();

    // deterministic centroid partial agg: int64 fixed-point 2^26 (order-free)
    for (int v = t; v < 1024; v += 512) {
        int l = v >> 6, d = v & 63;
        float s = 0.f;
        #pragma unroll
        for (int rr = 0; rr < 4; ++rr) s = fmaf(ohmf[rr*16 + l], shh[rr*64 + d], s);
        atomicAdd(&agg[v], (unsigned long long)__float2ll_rn(s * 67108864.0f));
    }
}

// ---------------------------------------------------------------------------
// k_scores: rebuild centroids per block from agg/cnt, then cdist.
// grid 128 x 256 : block = 16 rows x 16 labels x 16 lane-segs... (i=t>>4,l=t&15)
// ---------------------------------------------------------------------------
__global__ __launch_bounds__(256) void k_scores(
    unsigned char* __restrict__ ws, const float* __restrict__ hout,
    float* __restrict__ scores, float* __restrict__ missing)
{
    __shared__ float cl[16*68];
    unsigned long long* cnt = (unsigned long long*)(ws + WS_CNT);
    unsigned long long* agg = (unsigned long long*)(ws + WS_AGG);
    int t = threadIdx.x;

    for (int v = t; v < 1024; v += 256) {
        int l = v >> 6, d = v & 63;
        long long a = (long long)agg[v];
        long long c = (long long)cnt[l];
        // (a/2^26)/(c/2^20) = (a/c) * 2^-6 ; f32 precision ample for 1.4e-2 thr
        cl[l*68 + d] = (c == 0) ? 0.f : ((float)a / (float)c) * 0.015625f;
    }
    if (blockIdx.x == 0 && t < 16) missing[t] = (cnt[t] == 0) ? 1.0f : 0.0f;
    __syncthreads();

    int i = blockIdx.x*16 + (t >> 4), l = t & 15;
    float s = 0.f;
    #pragma unroll 16
    for (int d = 0; d < 64; ++d) {
        float diff = hout[i*64 + d] - cl[l*68 + d];
        s = fmaf(diff, diff, s);
    }
    scores[i*16 + l] = -sqrtf(s);
}

// ---------------------------------------------------------------------------
extern "C" void kernel_launch(void* const* d_in, const int* in_sizes, int n_in,
                              void* d_out, int out_size, void* d_ws, size_t ws_size,
                              hipStream_t stream)
{
    const float* x     = (const float*)d_in[0];
    const float* ohm   = (const float*)d_in[1];
    const float* Wl    = (const float*)d_in[2];
    const float* Wattn = (const float*)d_in[3];
    unsigned char* ws  = (unsigned char*)d_ws;

    float* out     = (float*)d_out;
    float* scores  = out;
    float* hout    = out + 2048*16;
    float* missing = out + 2048*16 + 2048*64;

    hipMemsetAsync(d_ws, 0, 8320, stream);           // cnt + agg
    k_proj  <<<512, 256, 0, stream>>>(x, ohm, Wl, Wattn, ws);
    k_attn  <<<512, 512, 0, stream>>>(ohm, Wattn, ws, hout);
    k_scores<<<128, 256, 0, stream>>>(ws, hout, scores, missing);
}